// Round 1
// baseline (764.885 us; speedup 1.0000x reference)
//
#include <hip/hip_runtime.h>
#include <math.h>

#define NN    768
#define CS    384
#define INF_  100000.0f

typedef __attribute__((ext_vector_type(8))) short s16x8;
typedef __attribute__((ext_vector_type(4))) float f32x4;

// ws offsets in floats
#define OFF_Q       0         // 768*192
#define OFF_K       147456    // 768*192
#define OFF_V       294912    // 768*192
#define OFF_QPRAW   442368    // 768*144
#define OFF_KVPRAW  552960    // 768*432
#define OFF_QPTS    884736    // 768*48*3
#define OFF_KPTS    995328    // 768*48*3
#define OFF_VPTS    1105920   // 768*96*3
#define OFF_KT      1327104   // 192*768 (K transposed [h*16+c][k])
#define OFF_KPT     1474560   // 144*768 (K_pts transposed [h*12+r][k])
#define OFF_S       1585152   // bf16 S[q][h][k] = 7077888 bf16 = 3538944 floats -> ends 5124096
#define OFF_CAT     8414208   // 768*2112

__device__ __forceinline__ unsigned short f2bf(float x) {
  unsigned u = __float_as_uint(x) + 0x8000u;
  return (unsigned short)(u >> 16);
}
__device__ __forceinline__ unsigned pk2(float a, float b) {
  return (unsigned)f2bf(a) | ((unsigned)f2bf(b) << 16);
}
__device__ __forceinline__ float bf2f(unsigned short u) {
  return __uint_as_float(((unsigned)u) << 16);
}

// LDS-only barrier: make this wave's DS ops visible, then rendezvous.
// Deliberately does NOT drain vmcnt -> global prefetch loads stay in flight
// across the barrier (T4 discipline; __syncthreads would vmcnt(0)-drain).
#define LDS_BARRIER() do { \
  asm volatile("s_waitcnt lgkmcnt(0)" ::: "memory"); \
  __builtin_amdgcn_s_barrier(); \
} while (0)

// ---------------------------------------------------------------- K1: projections, tiled GEMM (unchanged)
__global__ void __launch_bounds__(256)
k1_proj(const float* __restrict__ s,
        const float* __restrict__ Wq,  const float* __restrict__ bq,
        const float* __restrict__ Wqp, const float* __restrict__ bqp,
        const float* __restrict__ Wkv, const float* __restrict__ bkv,
        const float* __restrict__ Wkvp,const float* __restrict__ bkvp,
        float* __restrict__ ws) {
  const int n0 = blockIdx.x * 16;
  const int m0 = blockIdx.y * 128;
  const int t  = threadIdx.x;

  const float* W; const float* bv; int base, ncols;
  if (n0 < 192)      { W = Wq;   bv = bq;   base = 0;   ncols = 192; }
  else if (n0 < 576) { W = Wkv;  bv = bkv;  base = 192; ncols = 384; }
  else if (n0 < 720) { W = Wqp;  bv = bqp;  base = 576; ncols = 144; }
  else               { W = Wkvp; bv = bkvp; base = 720; ncols = 432; }
  const int jj0 = n0 - base;

  __shared__ float As[32 * 130];
  __shared__ float Bs[32 * 20];
  const int tx = t & 3, ty = t >> 2;
  float acc[2][4] = {{0.f}};

  for (int kc = 0; kc < CS; kc += 32) {
    __syncthreads();
    #pragma unroll
    for (int jj = 0; jj < 4; ++jj) {
      const int idx = t + 256 * jj;
      const int row = idx >> 3, c4 = idx & 7;
      const float4 v = *(const float4*)&s[(size_t)(m0 + row) * CS + kc + c4 * 4];
      As[(c4 * 4 + 0) * 130 + row] = v.x;
      As[(c4 * 4 + 1) * 130 + row] = v.y;
      As[(c4 * 4 + 2) * 130 + row] = v.z;
      As[(c4 * 4 + 3) * 130 + row] = v.w;
    }
    if (t < 128) {
      const int row = t >> 2, c4 = t & 3;
      const float4 v = *(const float4*)&W[(size_t)(kc + row) * ncols + jj0 + c4 * 4];
      *(float4*)&Bs[row * 20 + c4 * 4] = v;
    }
    __syncthreads();
    #pragma unroll 8
    for (int k = 0; k < 32; ++k) {
      const float2 a2 = *(const float2*)&As[k * 130 + ty * 2];
      const float4 b4 = *(const float4*)&Bs[k * 20 + tx * 4];
      acc[0][0] += a2.x * b4.x; acc[0][1] += a2.x * b4.y;
      acc[0][2] += a2.x * b4.z; acc[0][3] += a2.x * b4.w;
      acc[1][0] += a2.y * b4.x; acc[1][1] += a2.y * b4.y;
      acc[1][2] += a2.y * b4.z; acc[1][3] += a2.y * b4.w;
    }
  }

  #pragma unroll
  for (int r = 0; r < 2; ++r) {
    const int n = m0 + ty * 2 + r;
    #pragma unroll
    for (int e = 0; e < 4; ++e) {
      const int j = n0 + tx * 4 + e;
      const float val = acc[r][e] + bv[j - base];
      if (j < 192) {
        (ws + OFF_Q)[n * 192 + j] = val;
      } else if (j < 576) {
        const int jj = j - 192, h = jj >> 5, c = jj & 31;
        if (c < 16) (ws + OFF_K)[n * 192 + h * 16 + c] = val;
        else        (ws + OFF_V)[n * 192 + h * 16 + (c - 16)] = val;
      } else if (j < 720) {
        (ws + OFF_QPRAW)[n * 144 + (j - 576)] = val;
      } else {
        (ws + OFF_KVPRAW)[n * 432 + (j - 720)] = val;
      }
    }
  }
}

// ---------------------------------------------------------------- K2: rotate points (unchanged)
__global__ void __launch_bounds__(256)
k2_rot(const float* __restrict__ rot, const float* __restrict__ trans,
       float* __restrict__ ws) {
  const int idx = blockIdx.x * 256 + threadIdx.x;
  const int n = idx / 192;
  const int r = idx % 192;
  const float* R = rot + n * 9;
  const float* T = trans + n * 3;
  if (r < 48) {
    const float* raw = ws + OFF_QPRAW + n * 144;
    float p0 = raw[r], p1 = raw[48 + r], p2 = raw[96 + r];
    float g0 = R[0]*p0 + R[1]*p1 + R[2]*p2 + T[0];
    float g1 = R[3]*p0 + R[4]*p1 + R[5]*p2 + T[1];
    float g2 = R[6]*p0 + R[7]*p1 + R[8]*p2 + T[2];
    float* qp = ws + OFF_QPTS + n * 144 + r * 3;
    qp[0] = g0; qp[1] = g1; qp[2] = g2;
  } else {
    const int r2 = r - 48;
    const float* raw = ws + OFF_KVPRAW + n * 432;
    float p0 = raw[r2], p1 = raw[144 + r2], p2 = raw[288 + r2];
    float g0 = R[0]*p0 + R[1]*p1 + R[2]*p2 + T[0];
    float g1 = R[3]*p0 + R[4]*p1 + R[5]*p2 + T[1];
    float g2 = R[6]*p0 + R[7]*p1 + R[8]*p2 + T[2];
    const int h = r2 / 12, p = r2 % 12;
    if (p < 4) {
      float* kp = ws + OFF_KPTS + n * 144 + (h * 4 + p) * 3;
      kp[0] = g0; kp[1] = g1; kp[2] = g2;
    } else {
      float* vp = ws + OFF_VPTS + n * 288 + (h * 8 + (p - 4)) * 3;
      vp[0] = g0; vp[1] = g1; vp[2] = g2;
    }
  }
}

// ---------------------------------------------------------------- K2b: transpose K, K_pts to [feat][k] (unchanged)
__global__ void __launch_bounds__(256)
k2b_tr(float* __restrict__ ws) {
  const int i = blockIdx.x * 256 + threadIdx.x;
  if (i < 147456) {
    const int n = i / 192, cc = i % 192;
    (ws + OFF_KT)[cc * 768 + n] = (ws + OFF_K)[i];
  } else {
    const int i2 = i - 147456;
    const int n = i2 / 144, r = i2 % 144;
    (ws + OFF_KPT)[r * 768 + n] = (ws + OFF_KPTS)[i2];
  }
}

// ---------------------------------------------------------------- KS: S[q][h][k] = c1*qk - 0.5*hw*pt + c2*bb + mask  (bf16)
__global__ void __launch_bounds__(256)
ks_scores(const float* __restrict__ mask, const float* __restrict__ bb,
          const float* __restrict__ hwin, float* __restrict__ ws) {
  const int k0 = blockIdx.x * 64;
  const int q0 = blockIdx.y * 16;
  const int t = threadIdx.x;
  const int g = t >> 6, kl = t & 63;
  const int kg = k0 + kl;

  const float* ktr  = ws + OFF_KT;
  const float* kptr = ws + OFF_KPT;
  float F[3][28];
  #pragma unroll
  for (int j = 0; j < 3; ++j) {
    const int h = g + 4 * j;
    #pragma unroll
    for (int c = 0; c < 16; ++c) F[j][c] = ktr[(h * 16 + c) * 768 + kg];
    #pragma unroll
    for (int r = 0; r < 12; ++r) F[j][16 + r] = kptr[(h * 12 + r) * 768 + kg];
  }
  float hw3[3], bb3[3];
  #pragma unroll
  for (int j = 0; j < 3; ++j) {
    const int h = g + 4 * j;
    hw3[j] = logf(1.0f + expf(hwin[h])) * 0.13608276348795434f;  // softplus*sqrt(1/54)
    bb3[j] = 0.57735026918962576f * bb[h];
  }
  const float maskk = mask[kg];
  unsigned short* Sg = (unsigned short*)(ws + OFF_S);

  for (int qi = 0; qi < 16; ++qi) {
    const int q = q0 + qi;
    const float mterm = INF_ * (mask[q] * maskk - 1.0f);
    const float* qrow  = ws + OFF_Q    + q * 192;   // uniform -> s_loads
    const float* qprow = ws + OFF_QPTS + q * 144;
    #pragma unroll
    for (int j = 0; j < 3; ++j) {
      const int h = g + 4 * j;
      float qk = 0.f;
      #pragma unroll
      for (int c = 0; c < 16; ++c) qk += qrow[h * 16 + c] * F[j][c];
      float pt = 0.f;
      #pragma unroll
      for (int r = 0; r < 12; ++r) {
        const float d = qprow[h * 12 + r] - F[j][16 + r];
        pt += d * d;
      }
      const float S = 0.14433756729740643f * qk - 0.5f * hw3[j] * pt
                    + bb3[j] + mterm;
      Sg[(size_t)(q * 12 + h) * 768 + kg] = f2bf(S);
    }
  }
}

// ---------------------------------------------------------------- K3: fused single-z-pass attention
// One q per block, chunks of 64 k. z staged bf16 in zR (row-major, bias MFMA
// B-frags) and zT (transposed, pi(k), o_pair B-frags).
// NEW this round: register double-buffer prefetch of next chunk's z (8xfloat4)
// and S (3 bf16), issued right after the LDS pack so the HBM latency hides
// under bias-MFMA + w + phase C. In-loop barriers are raw s_barrier +
// lgkmcnt(0) (LDS-only) so the prefetch survives the barriers (no vmcnt drain).
#define ZT_S 72
#define ZR_S 136
#define WT_S 72
#define WH_S 68
__global__ void __launch_bounds__(256, 3)
k3_fused(const float* __restrict__ z, const float* __restrict__ rot,
         const float* __restrict__ trans, const float* __restrict__ Wb,
         float* __restrict__ ws) {
  const int q = blockIdx.x, t = threadIdx.x;
  const int g = t >> 6, kl = t & 63;
  const int l15 = kl & 15, lq = kl >> 4;

  __shared__ unsigned short zT[128 * ZT_S];   // 18432 B
  __shared__ unsigned short zR[64 * ZR_S];    // 17408 B
  __shared__ unsigned short wT[16 * WT_S];    // 2304 B
  __shared__ float wH[12 * WH_S];             // 3264 B
  __shared__ float bias_s[64 * 13];           // 3328 B
  __shared__ float lsum[12], linv[12];
  __shared__ float opt_raw[288];

  // resident bias A-frags: A[m=h][c] = Wb[c][h] (rows 12..15 zero)
  s16x8 wbA[4];
  #pragma unroll
  for (int kk = 0; kk < 4; ++kk) {
    #pragma unroll
    for (int j = 0; j < 8; ++j) {
      float v = (l15 < 12) ? Wb[(kk * 32 + lq * 8 + j) * 12 + l15] : 0.0f;
      wbA[kk][j] = (short)f2bf(v);
    }
  }

  const float* vbase = ws + OFF_V;
  const float* vpbase= ws + OFF_VPTS;
  const unsigned short* Sg = (const unsigned short*)(ws + OFF_S);
  const float4* zg4  = (const float4*)z + (size_t)q * 24576;

  float l3[3] = {0.f, 0.f, 0.f};
  f32x4 opA = {0.f,0.f,0.f,0.f}, opB = {0.f,0.f,0.f,0.f};
  float o_acc = 0.f, pt0 = 0.f, pt1 = 0.f;
  const int oh = t >> 4;
  const int ph = t / 24;
  const int p2s = 256 + t, p2h = p2s / 24;

  const int kb = t >> 5, c4 = t & 31;

  // ---- prologue: load chunk 0 into regs
  float4 zv[8];
  #pragma unroll
  for (int m = 0; m < 8; ++m)
    zv[m] = zg4[(size_t)(kb + 8 * m) * 32 + c4];
  unsigned short Sn[3];
  #pragma unroll
  for (int j = 0; j < 3; ++j)
    Sn[j] = Sg[(size_t)(q * 12 + (g + 4 * j)) * 768 + kl];

  for (int k0 = 0; k0 < NN; k0 += 64) {
    LDS_BARRIER();   // prev phase C done reading zT/wT/wH

    // ---- pack staged regs -> zR + zT (zT e-rotated, pi(k)=(k&7)*8+(k>>3))
    #pragma unroll
    for (int half = 0; half < 2; ++half) {
      #pragma unroll
      for (int j = 0; j < 4; ++j) {
        const float4 v = zv[half * 4 + j];
        uint2 d;
        d.x = pk2(v.x, v.y);
        d.y = pk2(v.z, v.w);
        *(uint2*)&zR[(kb + 8 * (half * 4 + j)) * ZR_S + c4 * 4] = d;
      }
      #pragma unroll
      for (int w = 0; w < 4; ++w) {
        const int e = ((c4 >> 1) + w) & 3;
        uint2 d;
        d.x = pk2(((const float*)&zv[half * 4 + 0])[e], ((const float*)&zv[half * 4 + 1])[e]);
        d.y = pk2(((const float*)&zv[half * 4 + 2])[e], ((const float*)&zv[half * 4 + 3])[e]);
        *(uint2*)&zT[(c4 * 4 + e) * ZT_S + kb * 8 + half * 4] = d;
      }
    }
    unsigned short Scur[3];
    #pragma unroll
    for (int j = 0; j < 3; ++j) Scur[j] = Sn[j];
    LDS_BARRIER();   // pack visible

    // ---- prefetch next chunk into regs; in flight across bias/w/phase C
    if (k0 + 64 < NN) {
      #pragma unroll
      for (int m = 0; m < 8; ++m)
        zv[m] = zg4[(size_t)(k0 + 64 + kb + 8 * m) * 32 + c4];
      #pragma unroll
      for (int j = 0; j < 3; ++j)
        Sn[j] = Sg[(size_t)(q * 12 + (g + 4 * j)) * 768 + k0 + 64 + kl];
    }

    // ---- bias MFMA: wave g -> k-tile g; D row = h, col = k-in-tile
    {
      f32x4 bd = {0.f,0.f,0.f,0.f};
      #pragma unroll
      for (int kk = 0; kk < 4; ++kk) {
        s16x8 bf = *(const s16x8*)&zR[(g * 16 + l15) * ZR_S + kk * 32 + lq * 8];
        bd = __builtin_amdgcn_mfma_f32_16x16x32_bf16(wbA[kk], bf, bd, 0, 0, 0);
      }
      #pragma unroll
      for (int r = 0; r < 4; ++r) {
        const int h = lq * 4 + r;
        if (h < 12) bias_s[(g * 16 + l15) * 13 + h] = bd[r];
      }
    }
    LDS_BARRIER();   // bias_s visible

    // ---- w = exp(S + c2*bias); store wT (bf16, pi-order) + wH (f32)
    {
      #pragma unroll
      for (int j = 0; j < 3; ++j) {
        const int h = g + 4 * j;
        const float Sv = bf2f(Scur[j]);
        const float wv = __expf(Sv + 0.57735026918962576f * bias_s[kl * 13 + h]);
        l3[j] += wv;
        wH[h * WH_S + kl] = wv;
        wT[h * WT_S + ((kl & 7) * 8 + (kl >> 3))] = f2bf(wv);
      }
    }
    LDS_BARRIER();   // wT/wH visible

    // ---- phase C: o_pair MFMA + o/o_pt VALU
    #pragma unroll
    for (int kk = 0; kk < 2; ++kk) {
      s16x8 af = *(const s16x8*)&wT[l15 * WT_S + kk * 32 + lq * 8];
      s16x8 b0 = *(const s16x8*)&zT[((2 * g)     * 16 + l15) * ZT_S + kk * 32 + lq * 8];
      opA = __builtin_amdgcn_mfma_f32_16x16x32_bf16(af, b0, opA, 0, 0, 0);
      s16x8 b1 = *(const s16x8*)&zT[((2 * g + 1) * 16 + l15) * ZT_S + kk * 32 + lq * 8];
      opB = __builtin_amdgcn_mfma_f32_16x16x32_bf16(af, b1, opB, 0, 0, 0);
    }
    {
      const float* vpr = vpbase + (size_t)k0 * 288;
      const float* vr  = vbase  + (size_t)k0 * 192;
      #pragma unroll 4
      for (int k4 = 0; k4 < 16; ++k4) {
        const int k = k4 * 4;
        {
          const float4 w4 = *(const float4*)&wH[ph * WH_S + k];
          pt0 += w4.x * vpr[(k    ) * 288 + t] + w4.y * vpr[(k + 1) * 288 + t]
               + w4.z * vpr[(k + 2) * 288 + t] + w4.w * vpr[(k + 3) * 288 + t];
        }
        if (t < 32) {
          const float4 w4 = *(const float4*)&wH[p2h * WH_S + k];
          pt1 += w4.x * vpr[(k    ) * 288 + p2s] + w4.y * vpr[(k + 1) * 288 + p2s]
               + w4.z * vpr[(k + 2) * 288 + p2s] + w4.w * vpr[(k + 3) * 288 + p2s];
        }
        if (t < 192) {
          const float4 w4 = *(const float4*)&wH[oh * WH_S + k];
          o_acc += w4.x * vr[(k    ) * 192 + t] + w4.y * vr[(k + 1) * 192 + t]
                 + w4.z * vr[(k + 2) * 192 + t] + w4.w * vr[(k + 3) * 192 + t];
        }
      }
    }
  }

  // ---- l reduction
  #pragma unroll
  for (int j = 0; j < 3; ++j) {
    float v = l3[j];
    for (int off = 1; off < 64; off <<= 1) v += __shfl_xor(v, off, 64);
    l3[j] = v;
  }
  if (kl == 0) { lsum[g] = l3[0]; lsum[g + 4] = l3[1]; lsum[g + 8] = l3[2]; }
  __syncthreads();
  if (t < 12) linv[t] = 1.0f / lsum[t];
  __syncthreads();

  float* cat = ws + OFF_CAT + (size_t)q * 2112;
  #pragma unroll
  for (int r = 0; r < 4; ++r) {
    const int h = lq * 4 + r;
    if (h < 12) {
      cat[576 + h * 128 + (2 * g)     * 16 + l15] = opA[r] * linv[h];
      cat[576 + h * 128 + (2 * g + 1) * 16 + l15] = opB[r] * linv[h];
    }
  }
  if (t < 192) cat[t] = o_acc * linv[oh];
  opt_raw[t] = pt0 * linv[ph];
  if (t < 32) opt_raw[p2s] = pt1 * linv[p2h];
  __syncthreads();

  if (t < 96) {
    const int h = t >> 3, p = t & 7;
    const float* R = rot + q * 9;
    const float* T = trans + q * 3;
    const float g0 = opt_raw[h * 24 + p * 3 + 0] - T[0];
    const float g1 = opt_raw[h * 24 + p * 3 + 1] - T[1];
    const float g2 = opt_raw[h * 24 + p * 3 + 2] - T[2];
    const float x  = R[0]*g0 + R[3]*g1 + R[6]*g2;
    const float y  = R[1]*g0 + R[4]*g1 + R[7]*g2;
    const float zc = R[2]*g0 + R[5]*g1 + R[8]*g2;
    const int hp = h * 8 + p;
    cat[192 + hp] = x;
    cat[288 + hp] = y;
    cat[384 + hp] = zc;
    cat[480 + hp] = sqrtf(x*x + y*y + zc*zc + 1e-8f);
  }
}

// ---------------------------------------------------------------- K5: out GEMM 64m x 64n, K-split 6, atomic
__global__ void __launch_bounds__(256)
k5_init(const float* __restrict__ bout, float* __restrict__ out) {
  const int i = blockIdx.x * 256 + threadIdx.x;  // 294912
  out[i] = bout[i % 384];
}

__global__ void __launch_bounds__(256)
k5_out(const float* __restrict__ Wout, const float* __restrict__ ws,
       float* __restrict__ out) {
  const int n0  = blockIdx.x * 64;    // 6
  const int m0  = blockIdx.y * 64;    // 12
  const int ks0 = blockIdx.z * 352;   // 6
  const int t = threadIdx.x;

  __shared__ float As[32 * 68];   // [k][m]
  __shared__ float Bs[32 * 68];   // [k][n]
  const int tx = t & 15, ty = t >> 4;
  float acc[4][4] = {{0.f}};

  const float* catg = ws + OFF_CAT;
  for (int kc = 0; kc < 352; kc += 32) {
    __syncthreads();
    #pragma unroll
    for (int p = 0; p < 2; ++p) {            // A: 64 m x 32 k (float4 read, scatter write)
      const int idx = t + 256 * p;
      const int m = idx >> 3, c4 = idx & 7;
      const float4 v = *(const float4*)&catg[(size_t)(m0 + m) * 2112 + ks0 + kc + c4 * 4];
      As[(c4 * 4 + 0) * 68 + m] = v.x;
      As[(c4 * 4 + 1) * 68 + m] = v.y;
      As[(c4 * 4 + 2) * 68 + m] = v.z;
      As[(c4 * 4 + 3) * 68 + m] = v.w;
    }
    #pragma unroll
    for (int p = 0; p < 8; ++p) {            // B: 32 k x 64 n (coalesced)
      const int idx = t + 256 * p;
      const int k = idx >> 6, n = idx & 63;
      Bs[k * 68 + n] = Wout[(size_t)(ks0 + kc + k) * 384 + n0 + n];
    }
    __syncthreads();
    #pragma unroll 8
    for (int k = 0; k < 32; ++k) {
      const float4 a4 = *(const float4*)&As[k * 68 + ty * 4];
      const float4 b4 = *(const float4*)&Bs[k * 68 + tx * 4];
      acc[0][0] += a4.x * b4.x; acc[0][1] += a4.x * b4.y; acc[0][2] += a4.x * b4.z; acc[0][3] += a4.x * b4.w;
      acc[1][0] += a4.y * b4.x; acc[1][1] += a4.y * b4.y; acc[1][2] += a4.y * b4.z; acc[1][3] += a4.y * b4.w;
      acc[2][0] += a4.z * b4.x; acc[2][1] += a4.z * b4.y; acc[2][2] += a4.z * b4.z; acc[2][3] += a4.z * b4.w;
      acc[3][0] += a4.w * b4.x; acc[3][1] += a4.w * b4.y; acc[3][2] += a4.w * b4.z; acc[3][3] += a4.w * b4.w;
    }
  }
  #pragma unroll
  for (int r = 0; r < 4; ++r)
    #pragma unroll
    for (int c = 0; c < 4; ++c)
      atomicAdd(&out[(size_t)(m0 + ty * 4 + r) * 384 + n0 + tx * 4 + c], acc[r][c]);
}

// ----------------------------------------------------------------
extern "C" void kernel_launch(void* const* d_in, const int* in_sizes, int n_in,
                              void* d_out, int out_size, void* d_ws, size_t ws_size,
                              hipStream_t stream) {
  const float* s     = (const float*)d_in[0];
  const float* z     = (const float*)d_in[1];
  const float* rot   = (const float*)d_in[2];
  const float* trans = (const float*)d_in[3];
  const float* mask  = (const float*)d_in[4];
  const float* Wq    = (const float*)d_in[5];
  const float* bq    = (const float*)d_in[6];
  const float* Wqp   = (const float*)d_in[7];
  const float* bqp   = (const float*)d_in[8];
  const float* Wkv   = (const float*)d_in[9];
  const float* bkv   = (const float*)d_in[10];
  const float* Wkvp  = (const float*)d_in[11];
  const float* bkvp  = (const float*)d_in[12];
  const float* Wb    = (const float*)d_in[13];
  const float* bb    = (const float*)d_in[14];
  const float* hw    = (const float*)d_in[15];
  const float* Wout  = (const float*)d_in[16];
  const float* bout  = (const float*)d_in[17];
  float* out = (float*)d_out;
  float* ws  = (float*)d_ws;

  k1_proj<<<dim3(72, 6), 256, 0, stream>>>(s, Wq, bq, Wqp, bqp, Wkv, bkv, Wkvp, bkvp, ws);
  k2_rot <<<576, 256, 0, stream>>>(rot, trans, ws);
  k2b_tr <<<1008, 256, 0, stream>>>(ws);
  ks_scores<<<dim3(12, 48), 256, 0, stream>>>(mask, bb, hw, ws);
  k3_fused<<<NN, 256, 0, stream>>>(z, rot, trans, Wb, ws);
  k5_init<<<1152, 256, 0, stream>>>(bout, out);
  k5_out<<<dim3(6, 12, 6), 256, 0, stream>>>(Wout, ws, out);
}

// Round 2
// 713.867 us; speedup vs baseline: 1.0715x; 1.0715x over previous
//
#include <hip/hip_runtime.h>
#include <math.h>

#define NN    768
#define CS    384
#define INF_  100000.0f

typedef __attribute__((ext_vector_type(8))) short s16x8;
typedef __attribute__((ext_vector_type(4))) float f32x4;

// ws offsets in floats
#define OFF_Q       0         // 768*192
#define OFF_K       147456    // 768*192
#define OFF_V       294912    // 768*192
#define OFF_QPRAW   442368    // 768*144
#define OFF_KVPRAW  552960    // 768*432
#define OFF_QPTS    884736    // 768*48*3
#define OFF_KPTS    995328    // 768*48*3
#define OFF_VPTS    1105920   // 768*96*3
#define OFF_KT      1327104   // 192*768 (K transposed [h*16+c][k])
#define OFF_KPT     1474560   // 144*768 (K_pts transposed [h*12+r][k])
#define OFF_S       1585152   // bf16 S[q][h][k] -> 3538944 floats, ends 5124096
#define OFF_MT      5124096   // bf16 M[512][768] merged V|VPTS transposed, pi-permuted k; 196608 floats
#define OFF_CAT     8414208   // 768*2112

__device__ __forceinline__ unsigned short f2bf(float x) {
  unsigned u = __float_as_uint(x) + 0x8000u;
  return (unsigned short)(u >> 16);
}
__device__ __forceinline__ unsigned pk2(float a, float b) {
  return (unsigned)f2bf(a) | ((unsigned)f2bf(b) << 16);
}
__device__ __forceinline__ float bf2f(unsigned short u) {
  return __uint_as_float(((unsigned)u) << 16);
}

// ---------------------------------------------------------------- K1: projections, tiled GEMM (unchanged)
__global__ void __launch_bounds__(256)
k1_proj(const float* __restrict__ s,
        const float* __restrict__ Wq,  const float* __restrict__ bq,
        const float* __restrict__ Wqp, const float* __restrict__ bqp,
        const float* __restrict__ Wkv, const float* __restrict__ bkv,
        const float* __restrict__ Wkvp,const float* __restrict__ bkvp,
        float* __restrict__ ws) {
  const int n0 = blockIdx.x * 16;
  const int m0 = blockIdx.y * 128;
  const int t  = threadIdx.x;

  const float* W; const float* bv; int base, ncols;
  if (n0 < 192)      { W = Wq;   bv = bq;   base = 0;   ncols = 192; }
  else if (n0 < 576) { W = Wkv;  bv = bkv;  base = 192; ncols = 384; }
  else if (n0 < 720) { W = Wqp;  bv = bqp;  base = 576; ncols = 144; }
  else               { W = Wkvp; bv = bkvp; base = 720; ncols = 432; }
  const int jj0 = n0 - base;

  __shared__ float As[32 * 130];
  __shared__ float Bs[32 * 20];
  const int tx = t & 3, ty = t >> 2;
  float acc[2][4] = {{0.f}};

  for (int kc = 0; kc < CS; kc += 32) {
    __syncthreads();
    #pragma unroll
    for (int jj = 0; jj < 4; ++jj) {
      const int idx = t + 256 * jj;
      const int row = idx >> 3, c4 = idx & 7;
      const float4 v = *(const float4*)&s[(size_t)(m0 + row) * CS + kc + c4 * 4];
      As[(c4 * 4 + 0) * 130 + row] = v.x;
      As[(c4 * 4 + 1) * 130 + row] = v.y;
      As[(c4 * 4 + 2) * 130 + row] = v.z;
      As[(c4 * 4 + 3) * 130 + row] = v.w;
    }
    if (t < 128) {
      const int row = t >> 2, c4 = t & 3;
      const float4 v = *(const float4*)&W[(size_t)(kc + row) * ncols + jj0 + c4 * 4];
      *(float4*)&Bs[row * 20 + c4 * 4] = v;
    }
    __syncthreads();
    #pragma unroll 8
    for (int k = 0; k < 32; ++k) {
      const float2 a2 = *(const float2*)&As[k * 130 + ty * 2];
      const float4 b4 = *(const float4*)&Bs[k * 20 + tx * 4];
      acc[0][0] += a2.x * b4.x; acc[0][1] += a2.x * b4.y;
      acc[0][2] += a2.x * b4.z; acc[0][3] += a2.x * b4.w;
      acc[1][0] += a2.y * b4.x; acc[1][1] += a2.y * b4.y;
      acc[1][2] += a2.y * b4.z; acc[1][3] += a2.y * b4.w;
    }
  }

  #pragma unroll
  for (int r = 0; r < 2; ++r) {
    const int n = m0 + ty * 2 + r;
    #pragma unroll
    for (int e = 0; e < 4; ++e) {
      const int j = n0 + tx * 4 + e;
      const float val = acc[r][e] + bv[j - base];
      if (j < 192) {
        (ws + OFF_Q)[n * 192 + j] = val;
      } else if (j < 576) {
        const int jj = j - 192, h = jj >> 5, c = jj & 31;
        if (c < 16) (ws + OFF_K)[n * 192 + h * 16 + c] = val;
        else        (ws + OFF_V)[n * 192 + h * 16 + (c - 16)] = val;
      } else if (j < 720) {
        (ws + OFF_QPRAW)[n * 144 + (j - 576)] = val;
      } else {
        (ws + OFF_KVPRAW)[n * 432 + (j - 720)] = val;
      }
    }
  }
}

// ---------------------------------------------------------------- K2: rotate points (unchanged)
__global__ void __launch_bounds__(256)
k2_rot(const float* __restrict__ rot, const float* __restrict__ trans,
       float* __restrict__ ws) {
  const int idx = blockIdx.x * 256 + threadIdx.x;
  const int n = idx / 192;
  const int r = idx % 192;
  const float* R = rot + n * 9;
  const float* T = trans + n * 3;
  if (r < 48) {
    const float* raw = ws + OFF_QPRAW + n * 144;
    float p0 = raw[r], p1 = raw[48 + r], p2 = raw[96 + r];
    float g0 = R[0]*p0 + R[1]*p1 + R[2]*p2 + T[0];
    float g1 = R[3]*p0 + R[4]*p1 + R[5]*p2 + T[1];
    float g2 = R[6]*p0 + R[7]*p1 + R[8]*p2 + T[2];
    float* qp = ws + OFF_QPTS + n * 144 + r * 3;
    qp[0] = g0; qp[1] = g1; qp[2] = g2;
  } else {
    const int r2 = r - 48;
    const float* raw = ws + OFF_KVPRAW + n * 432;
    float p0 = raw[r2], p1 = raw[144 + r2], p2 = raw[288 + r2];
    float g0 = R[0]*p0 + R[1]*p1 + R[2]*p2 + T[0];
    float g1 = R[3]*p0 + R[4]*p1 + R[5]*p2 + T[1];
    float g2 = R[6]*p0 + R[7]*p1 + R[8]*p2 + T[2];
    const int h = r2 / 12, p = r2 % 12;
    if (p < 4) {
      float* kp = ws + OFF_KPTS + n * 144 + (h * 4 + p) * 3;
      kp[0] = g0; kp[1] = g1; kp[2] = g2;
    } else {
      float* vp = ws + OFF_VPTS + n * 288 + (h * 8 + (p - 4)) * 3;
      vp[0] = g0; vp[1] = g1; vp[2] = g2;
    }
  }
}

// ---------------------------------------------------------------- K2b: transpose K, K_pts; build M = [V|VPTS]^T bf16
// M[row][p]: row = h*40 + c (c<16: V col c; c>=16: o_pt comp (c-16)=p*3+d),
// rows 480..511 zero. p holds logical k = (p&~63) | pi64(p&63) so B-frag
// positions match wT's pi-permuted A-frag positions.
__global__ void __launch_bounds__(256)
k2b_tr(float* __restrict__ ws) {
  const int i = blockIdx.x * 256 + threadIdx.x;
  if (i < 147456) {
    const int n = i / 192, cc = i % 192;
    (ws + OFF_KT)[cc * 768 + n] = (ws + OFF_K)[i];
  } else if (i < 258048) {
    const int i2 = i - 147456;
    const int n = i2 / 144, r = i2 % 144;
    (ws + OFF_KPT)[r * 768 + n] = (ws + OFF_KPTS)[i2];
  } else {
    const int im = i - 258048;                 // [0, 393216)
    const int row = im / 768, p = im - row * 768;
    unsigned short* M = (unsigned short*)(ws + OFF_MT);
    float val = 0.0f;
    if (row < 480) {
      const int hh = row / 40, c = row - hh * 40;
      const int pl = p & 63;
      const int k = (p & ~63) | (((pl & 7) << 3) | (pl >> 3));   // inv-pi (involution)
      val = (c < 16) ? (ws + OFF_V)[k * 192 + hh * 16 + c]
                     : (ws + OFF_VPTS)[k * 288 + hh * 24 + (c - 16)];
    }
    M[row * 768 + p] = f2bf(val);
  }
}

// ---------------------------------------------------------------- KS: S[q][h][k] (unchanged)
__global__ void __launch_bounds__(256)
ks_scores(const float* __restrict__ mask, const float* __restrict__ bb,
          const float* __restrict__ hwin, float* __restrict__ ws) {
  const int k0 = blockIdx.x * 64;
  const int q0 = blockIdx.y * 16;
  const int t = threadIdx.x;
  const int g = t >> 6, kl = t & 63;
  const int kg = k0 + kl;

  const float* ktr  = ws + OFF_KT;
  const float* kptr = ws + OFF_KPT;
  float F[3][28];
  #pragma unroll
  for (int j = 0; j < 3; ++j) {
    const int h = g + 4 * j;
    #pragma unroll
    for (int c = 0; c < 16; ++c) F[j][c] = ktr[(h * 16 + c) * 768 + kg];
    #pragma unroll
    for (int r = 0; r < 12; ++r) F[j][16 + r] = kptr[(h * 12 + r) * 768 + kg];
  }
  float hw3[3], bb3[3];
  #pragma unroll
  for (int j = 0; j < 3; ++j) {
    const int h = g + 4 * j;
    hw3[j] = logf(1.0f + expf(hwin[h])) * 0.13608276348795434f;  // softplus*sqrt(1/54)
    bb3[j] = 0.57735026918962576f * bb[h];
  }
  const float maskk = mask[kg];
  unsigned short* Sg = (unsigned short*)(ws + OFF_S);

  for (int qi = 0; qi < 16; ++qi) {
    const int q = q0 + qi;
    const float mterm = INF_ * (mask[q] * maskk - 1.0f);
    const float* qrow  = ws + OFF_Q    + q * 192;   // uniform -> s_loads
    const float* qprow = ws + OFF_QPTS + q * 144;
    #pragma unroll
    for (int j = 0; j < 3; ++j) {
      const int h = g + 4 * j;
      float qk = 0.f;
      #pragma unroll
      for (int c = 0; c < 16; ++c) qk += qrow[h * 16 + c] * F[j][c];
      float pt = 0.f;
      #pragma unroll
      for (int r = 0; r < 12; ++r) {
        const float d = qprow[h * 12 + r] - F[j][16 + r];
        pt += d * d;
      }
      const float S = 0.14433756729740643f * qk - 0.5f * hw3[j] * pt
                    + bb3[j] + mterm;
      Sg[(size_t)(q * 12 + h) * 768 + kg] = f2bf(S);
    }
  }
}

// ---------------------------------------------------------------- K3: fused single-z-pass attention
// R2: phase C's o/o_pt VALU loop (192 scalar L2 loads/thread/iter, the
// latency serializer) replaced by MFMA over M (bf16 [V|VPTS]^T): the wT
// A-frags (A[m=h][k]=w) multiply M B-frags read directly from L2 as 16
// dwordx4/thread/iter, accumulating in 8 resident f32x4 D-regs across all
// chunks. wH and the k4 loop are gone. Cross-iter prefetch (R1) reverted.
#define ZT_S 72
#define ZR_S 136
#define WT_S 72
__global__ void __launch_bounds__(256, 3)
k3_fused(const float* __restrict__ z, const float* __restrict__ rot,
         const float* __restrict__ trans, const float* __restrict__ Wb,
         float* __restrict__ ws) {
  const int q = blockIdx.x, t = threadIdx.x;
  const int g = t >> 6, kl = t & 63;
  const int l15 = kl & 15, lq = kl >> 4;

  __shared__ unsigned short zT[128 * ZT_S];   // 18432 B
  __shared__ unsigned short zR[64 * ZR_S];    // 17408 B
  __shared__ unsigned short wT[16 * WT_S];    // 2304 B
  __shared__ float bias_s[64 * 13];           // 3328 B
  __shared__ float lsum[12], linv[12];
  __shared__ float opt_raw[288];

  // resident bias A-frags: A[m=h][c] = Wb[c][h] (rows 12..15 zero)
  s16x8 wbA[4];
  #pragma unroll
  for (int kk = 0; kk < 4; ++kk) {
    #pragma unroll
    for (int j = 0; j < 8; ++j) {
      float v = (l15 < 12) ? Wb[(kk * 32 + lq * 8 + j) * 12 + l15] : 0.0f;
      wbA[kk][j] = (short)f2bf(v);
    }
  }

  const unsigned short* Sg = (const unsigned short*)(ws + OFF_S);
  const float4* zg4  = (const float4*)z + (size_t)q * 24576;
  const unsigned short* mbase = (const unsigned short*)(ws + OFF_MT)
                              + (size_t)(g * 128 + l15) * 768 + lq * 8;

  float l3[3] = {0.f, 0.f, 0.f};
  f32x4 opA = {0.f,0.f,0.f,0.f}, opB = {0.f,0.f,0.f,0.f};
  f32x4 acc[8];
  #pragma unroll
  for (int i = 0; i < 8; ++i) acc[i] = (f32x4){0.f,0.f,0.f,0.f};

  const int kb = t >> 5, c4 = t & 31;

  for (int k0 = 0; k0 < NN; k0 += 64) {
    __syncthreads();   // prev phase C done reading zR/zT/wT

    // ---- load z chunk + S (same-iteration lifetime only)
    float4 zv[8];
    #pragma unroll
    for (int m = 0; m < 8; ++m)
      zv[m] = zg4[(size_t)(k0 + kb + 8 * m) * 32 + c4];
    unsigned short Sc[3];
    #pragma unroll
    for (int j = 0; j < 3; ++j)
      Sc[j] = Sg[(size_t)(q * 12 + (g + 4 * j)) * 768 + k0 + kl];

    // ---- pack -> zR + zT (zT e-rotated, pi(k)=(k&7)*8+(k>>3))
    #pragma unroll
    for (int half = 0; half < 2; ++half) {
      #pragma unroll
      for (int j = 0; j < 4; ++j) {
        const float4 v = zv[half * 4 + j];
        uint2 d;
        d.x = pk2(v.x, v.y);
        d.y = pk2(v.z, v.w);
        *(uint2*)&zR[(kb + 8 * (half * 4 + j)) * ZR_S + c4 * 4] = d;
      }
      #pragma unroll
      for (int w = 0; w < 4; ++w) {
        const int e = ((c4 >> 1) + w) & 3;
        uint2 d;
        d.x = pk2(((const float*)&zv[half * 4 + 0])[e], ((const float*)&zv[half * 4 + 1])[e]);
        d.y = pk2(((const float*)&zv[half * 4 + 2])[e], ((const float*)&zv[half * 4 + 3])[e]);
        *(uint2*)&zT[(c4 * 4 + e) * ZT_S + kb * 8 + half * 4] = d;
      }
    }
    __syncthreads();   // pack visible

    // ---- bias MFMA: wave g -> k-tile g; D row = h, col = k-in-tile
    {
      f32x4 bd = {0.f,0.f,0.f,0.f};
      #pragma unroll
      for (int kk = 0; kk < 4; ++kk) {
        s16x8 bf = *(const s16x8*)&zR[(g * 16 + l15) * ZR_S + kk * 32 + lq * 8];
        bd = __builtin_amdgcn_mfma_f32_16x16x32_bf16(wbA[kk], bf, bd, 0, 0, 0);
      }
      #pragma unroll
      for (int r = 0; r < 4; ++r) {
        const int h = lq * 4 + r;
        if (h < 12) bias_s[(g * 16 + l15) * 13 + h] = bd[r];
      }
    }
    __syncthreads();   // bias_s visible

    // ---- w = exp(S + c2*bias); store wT (bf16, pi-order); accumulate l
    {
      #pragma unroll
      for (int j = 0; j < 3; ++j) {
        const int h = g + 4 * j;
        const float Sv = bf2f(Sc[j]);
        const float wv = __expf(Sv + 0.57735026918962576f * bias_s[kl * 13 + h]);
        l3[j] += wv;
        wT[h * WT_S + ((kl & 7) * 8 + (kl >> 3))] = f2bf(wv);
      }
    }
    __syncthreads();   // wT visible

    // ---- phase C: all-MFMA. o_pair from zT (LDS), o/o_pt from M (L2).
    const s16x8 af0 = *(const s16x8*)&wT[l15 * WT_S + lq * 8];
    const s16x8 af1 = *(const s16x8*)&wT[l15 * WT_S + 32 + lq * 8];
    {
      s16x8 b0 = *(const s16x8*)&zT[((2 * g)     * 16 + l15) * ZT_S + lq * 8];
      s16x8 b1 = *(const s16x8*)&zT[((2 * g)     * 16 + l15) * ZT_S + 32 + lq * 8];
      s16x8 b2 = *(const s16x8*)&zT[((2 * g + 1) * 16 + l15) * ZT_S + lq * 8];
      s16x8 b3 = *(const s16x8*)&zT[((2 * g + 1) * 16 + l15) * ZT_S + 32 + lq * 8];
      opA = __builtin_amdgcn_mfma_f32_16x16x32_bf16(af0, b0, opA, 0, 0, 0);
      opA = __builtin_amdgcn_mfma_f32_16x16x32_bf16(af1, b1, opA, 0, 0, 0);
      opB = __builtin_amdgcn_mfma_f32_16x16x32_bf16(af0, b2, opB, 0, 0, 0);
      opB = __builtin_amdgcn_mfma_f32_16x16x32_bf16(af1, b3, opB, 0, 0, 0);
    }
    {
      const unsigned short* mp = mbase + k0;
      #pragma unroll
      for (int ti = 0; ti < 8; ++ti) {
        const s16x8 m0 = *(const s16x8*)(mp);
        const s16x8 m1 = *(const s16x8*)(mp + 32);
        acc[ti] = __builtin_amdgcn_mfma_f32_16x16x32_bf16(af0, m0, acc[ti], 0, 0, 0);
        acc[ti] = __builtin_amdgcn_mfma_f32_16x16x32_bf16(af1, m1, acc[ti], 0, 0, 0);
        mp += 16 * 768;
      }
    }
  }

  // ---- l reduction
  #pragma unroll
  for (int j = 0; j < 3; ++j) {
    float v = l3[j];
    for (int off = 1; off < 64; off <<= 1) v += __shfl_xor(v, off, 64);
    l3[j] = v;
  }
  if (kl == 0) { lsum[g] = l3[0]; lsum[g + 4] = l3[1]; lsum[g + 8] = l3[2]; }
  __syncthreads();
  if (t < 12) linv[t] = 1.0f / lsum[t];
  __syncthreads();

  float* cat = ws + OFF_CAT + (size_t)q * 2112;

  // o_pair
  #pragma unroll
  for (int r = 0; r < 4; ++r) {
    const int h = lq * 4 + r;
    if (h < 12) {
      cat[576 + h * 128 + (2 * g)     * 16 + l15] = opA[r] * linv[h];
      cat[576 + h * 128 + (2 * g + 1) * 16 + l15] = opB[r] * linv[h];
    }
  }

  // o / o_pt extraction: wave g owns col-tiles g*8..g*8+7; col cg -> (hh, c)
  #pragma unroll
  for (int ti = 0; ti < 8; ++ti) {
    const int cg = (g * 8 + ti) * 16 + l15;
    const int hh = cg / 40;
    const int c  = cg - hh * 40;
    #pragma unroll
    for (int r = 0; r < 4; ++r) {
      if (hh < 12 && (lq * 4 + r) == hh) {
        const float val = acc[ti][r] * linv[hh];
        if (c < 16) cat[hh * 16 + c] = val;
        else        opt_raw[hh * 24 + (c - 16)] = val;
      }
    }
  }
  __syncthreads();

  if (t < 96) {
    const int h = t >> 3, p = t & 7;
    const float* R = rot + q * 9;
    const float* T = trans + q * 3;
    const float g0 = opt_raw[h * 24 + p * 3 + 0] - T[0];
    const float g1 = opt_raw[h * 24 + p * 3 + 1] - T[1];
    const float g2 = opt_raw[h * 24 + p * 3 + 2] - T[2];
    const float x  = R[0]*g0 + R[3]*g1 + R[6]*g2;
    const float y  = R[1]*g0 + R[4]*g1 + R[7]*g2;
    const float zc = R[2]*g0 + R[5]*g1 + R[8]*g2;
    const int hp = h * 8 + p;
    cat[192 + hp] = x;
    cat[288 + hp] = y;
    cat[384 + hp] = zc;
    cat[480 + hp] = sqrtf(x*x + y*y + zc*zc + 1e-8f);
  }
}

// ---------------------------------------------------------------- K5: out GEMM 64m x 64n, K-split 6, atomic
__global__ void __launch_bounds__(256)
k5_init(const float* __restrict__ bout, float* __restrict__ out) {
  const int i = blockIdx.x * 256 + threadIdx.x;  // 294912
  out[i] = bout[i % 384];
}

__global__ void __launch_bounds__(256)
k5_out(const float* __restrict__ Wout, const float* __restrict__ ws,
       float* __restrict__ out) {
  const int n0  = blockIdx.x * 64;    // 6
  const int m0  = blockIdx.y * 64;    // 12
  const int ks0 = blockIdx.z * 352;   // 6
  const int t = threadIdx.x;

  __shared__ float As[32 * 68];   // [k][m]
  __shared__ float Bs[32 * 68];   // [k][n]
  const int tx = t & 15, ty = t >> 4;
  float acc[4][4] = {{0.f}};

  const float* catg = ws + OFF_CAT;
  for (int kc = 0; kc < 352; kc += 32) {
    __syncthreads();
    #pragma unroll
    for (int p = 0; p < 2; ++p) {            // A: 64 m x 32 k (float4 read, scatter write)
      const int idx = t + 256 * p;
      const int m = idx >> 3, c4 = idx & 7;
      const float4 v = *(const float4*)&catg[(size_t)(m0 + m) * 2112 + ks0 + kc + c4 * 4];
      As[(c4 * 4 + 0) * 68 + m] = v.x;
      As[(c4 * 4 + 1) * 68 + m] = v.y;
      As[(c4 * 4 + 2) * 68 + m] = v.z;
      As[(c4 * 4 + 3) * 68 + m] = v.w;
    }
    #pragma unroll
    for (int p = 0; p < 8; ++p) {            // B: 32 k x 64 n (coalesced)
      const int idx = t + 256 * p;
      const int k = idx >> 6, n = idx & 63;
      Bs[k * 68 + n] = Wout[(size_t)(ks0 + kc + k) * 384 + n0 + n];
    }
    __syncthreads();
    #pragma unroll 8
    for (int k = 0; k < 32; ++k) {
      const float4 a4 = *(const float4*)&As[k * 68 + ty * 4];
      const float4 b4 = *(const float4*)&Bs[k * 68 + tx * 4];
      acc[0][0] += a4.x * b4.x; acc[0][1] += a4.x * b4.y; acc[0][2] += a4.x * b4.z; acc[0][3] += a4.x * b4.w;
      acc[1][0] += a4.y * b4.x; acc[1][1] += a4.y * b4.y; acc[1][2] += a4.y * b4.z; acc[1][3] += a4.y * b4.w;
      acc[2][0] += a4.z * b4.x; acc[2][1] += a4.z * b4.y; acc[2][2] += a4.z * b4.z; acc[2][3] += a4.z * b4.w;
      acc[3][0] += a4.w * b4.x; acc[3][1] += a4.w * b4.y; acc[3][2] += a4.w * b4.z; acc[3][3] += a4.w * b4.w;
    }
  }
  #pragma unroll
  for (int r = 0; r < 4; ++r)
    #pragma unroll
    for (int c = 0; c < 4; ++c)
      atomicAdd(&out[(size_t)(m0 + ty * 4 + r) * 384 + n0 + tx * 4 + c], acc[r][c]);
}

// ----------------------------------------------------------------
extern "C" void kernel_launch(void* const* d_in, const int* in_sizes, int n_in,
                              void* d_out, int out_size, void* d_ws, size_t ws_size,
                              hipStream_t stream) {
  const float* s     = (const float*)d_in[0];
  const float* z     = (const float*)d_in[1];
  const float* rot   = (const float*)d_in[2];
  const float* trans = (const float*)d_in[3];
  const float* mask  = (const float*)d_in[4];
  const float* Wq    = (const float*)d_in[5];
  const float* bq    = (const float*)d_in[6];
  const float* Wqp   = (const float*)d_in[7];
  const float* bqp   = (const float*)d_in[8];
  const float* Wkv   = (const float*)d_in[9];
  const float* bkv   = (const float*)d_in[10];
  const float* Wkvp  = (const float*)d_in[11];
  const float* bkvp  = (const float*)d_in[12];
  const float* Wb    = (const float*)d_in[13];
  const float* bb    = (const float*)d_in[14];
  const float* hw    = (const float*)d_in[15];
  const float* Wout  = (const float*)d_in[16];
  const float* bout  = (const float*)d_in[17];
  float* out = (float*)d_out;
  float* ws  = (float*)d_ws;

  k1_proj<<<dim3(72, 6), 256, 0, stream>>>(s, Wq, bq, Wqp, bqp, Wkv, bkv, Wkvp, bkvp, ws);
  k2_rot <<<576, 256, 0, stream>>>(rot, trans, ws);
  k2b_tr <<<2544, 256, 0, stream>>>(ws);
  ks_scores<<<dim3(12, 48), 256, 0, stream>>>(mask, bb, hw, ws);
  k3_fused<<<NN, 256, 0, stream>>>(z, rot, trans, Wb, ws);
  k5_init<<<1152, 256, 0, stream>>>(bout, out);
  k5_out<<<dim3(6, 12, 6), 256, 0, stream>>>(Wout, ws, out);
}

// Round 3
// 695.520 us; speedup vs baseline: 1.0997x; 1.0264x over previous
//
#include <hip/hip_runtime.h>
#include <math.h>

#define NN    768
#define CS    384
#define INF_  100000.0f

typedef __attribute__((ext_vector_type(8))) short s16x8;
typedef __attribute__((ext_vector_type(4))) float f32x4;

// ws offsets in floats
#define OFF_Q       0         // 768*192
#define OFF_K       147456    // 768*192
#define OFF_V       294912    // 768*192
#define OFF_QPRAW   442368    // 768*144
#define OFF_KVPRAW  552960    // 768*432
#define OFF_QPTS    884736    // 768*48*3
#define OFF_KPTS    995328    // 768*48*3
#define OFF_VPTS    1105920   // 768*96*3
#define OFF_KT      1327104   // 192*768 (K transposed [h*16+c][k])
#define OFF_KPT     1474560   // 144*768 (K_pts transposed [h*12+r][k])
#define OFF_S       1585152   // bf16 S[q][h][k] -> 3538944 floats, ends 5124096
#define OFF_MT      5124096   // bf16 M[512][768] merged V|VPTS transposed, pi-permuted k
#define OFF_CAT     8414208   // 768*2112

__device__ __forceinline__ unsigned short f2bf(float x) {
  unsigned u = __float_as_uint(x) + 0x8000u;
  return (unsigned short)(u >> 16);
}
__device__ __forceinline__ unsigned pk2(float a, float b) {
  return (unsigned)f2bf(a) | ((unsigned)f2bf(b) << 16);
}
__device__ __forceinline__ float bf2f(unsigned short u) {
  return __uint_as_float(((unsigned)u) << 16);
}

// LDS-only barrier: drain DS ops for cross-wave visibility, then rendezvous.
// Does NOT drain vmcnt -> global_load_lds DMA + M loads stay in flight.
#define LDS_BARRIER() do { \
  asm volatile("s_waitcnt lgkmcnt(0)" ::: "memory"); \
  __builtin_amdgcn_s_barrier(); \
} while (0)

// global->LDS async DMA, 16B per lane. LDS dest = wave-uniform base + lane*16
// (CK amd_direct_load int-round-trip addrspace cast pattern).
__device__ __forceinline__ void gload_lds16(const void* g, void* l) {
  __builtin_amdgcn_global_load_lds(
      (const __attribute__((address_space(1))) void*)(unsigned long long)g,
      (__attribute__((address_space(3))) void*)(unsigned)(unsigned long long)l,
      16, 0, 0);
}

// ---------------------------------------------------------------- K1: projections, tiled GEMM (unchanged)
__global__ void __launch_bounds__(256)
k1_proj(const float* __restrict__ s,
        const float* __restrict__ Wq,  const float* __restrict__ bq,
        const float* __restrict__ Wqp, const float* __restrict__ bqp,
        const float* __restrict__ Wkv, const float* __restrict__ bkv,
        const float* __restrict__ Wkvp,const float* __restrict__ bkvp,
        float* __restrict__ ws) {
  const int n0 = blockIdx.x * 16;
  const int m0 = blockIdx.y * 128;
  const int t  = threadIdx.x;

  const float* W; const float* bv; int base, ncols;
  if (n0 < 192)      { W = Wq;   bv = bq;   base = 0;   ncols = 192; }
  else if (n0 < 576) { W = Wkv;  bv = bkv;  base = 192; ncols = 384; }
  else if (n0 < 720) { W = Wqp;  bv = bqp;  base = 576; ncols = 144; }
  else               { W = Wkvp; bv = bkvp; base = 720; ncols = 432; }
  const int jj0 = n0 - base;

  __shared__ float As[32 * 130];
  __shared__ float Bs[32 * 20];
  const int tx = t & 3, ty = t >> 2;
  float acc[2][4] = {{0.f}};

  for (int kc = 0; kc < CS; kc += 32) {
    __syncthreads();
    #pragma unroll
    for (int jj = 0; jj < 4; ++jj) {
      const int idx = t + 256 * jj;
      const int row = idx >> 3, c4 = idx & 7;
      const float4 v = *(const float4*)&s[(size_t)(m0 + row) * CS + kc + c4 * 4];
      As[(c4 * 4 + 0) * 130 + row] = v.x;
      As[(c4 * 4 + 1) * 130 + row] = v.y;
      As[(c4 * 4 + 2) * 130 + row] = v.z;
      As[(c4 * 4 + 3) * 130 + row] = v.w;
    }
    if (t < 128) {
      const int row = t >> 2, c4 = t & 3;
      const float4 v = *(const float4*)&W[(size_t)(kc + row) * ncols + jj0 + c4 * 4];
      *(float4*)&Bs[row * 20 + c4 * 4] = v;
    }
    __syncthreads();
    #pragma unroll 8
    for (int k = 0; k < 32; ++k) {
      const float2 a2 = *(const float2*)&As[k * 130 + ty * 2];
      const float4 b4 = *(const float4*)&Bs[k * 20 + tx * 4];
      acc[0][0] += a2.x * b4.x; acc[0][1] += a2.x * b4.y;
      acc[0][2] += a2.x * b4.z; acc[0][3] += a2.x * b4.w;
      acc[1][0] += a2.y * b4.x; acc[1][1] += a2.y * b4.y;
      acc[1][2] += a2.y * b4.z; acc[1][3] += a2.y * b4.w;
    }
  }

  #pragma unroll
  for (int r = 0; r < 2; ++r) {
    const int n = m0 + ty * 2 + r;
    #pragma unroll
    for (int e = 0; e < 4; ++e) {
      const int j = n0 + tx * 4 + e;
      const float val = acc[r][e] + bv[j - base];
      if (j < 192) {
        (ws + OFF_Q)[n * 192 + j] = val;
      } else if (j < 576) {
        const int jj = j - 192, h = jj >> 5, c = jj & 31;
        if (c < 16) (ws + OFF_K)[n * 192 + h * 16 + c] = val;
        else        (ws + OFF_V)[n * 192 + h * 16 + (c - 16)] = val;
      } else if (j < 720) {
        (ws + OFF_QPRAW)[n * 144 + (j - 576)] = val;
      } else {
        (ws + OFF_KVPRAW)[n * 432 + (j - 720)] = val;
      }
    }
  }
}

// ---------------------------------------------------------------- K2: rotate points (unchanged)
__global__ void __launch_bounds__(256)
k2_rot(const float* __restrict__ rot, const float* __restrict__ trans,
       float* __restrict__ ws) {
  const int idx = blockIdx.x * 256 + threadIdx.x;
  const int n = idx / 192;
  const int r = idx % 192;
  const float* R = rot + n * 9;
  const float* T = trans + n * 3;
  if (r < 48) {
    const float* raw = ws + OFF_QPRAW + n * 144;
    float p0 = raw[r], p1 = raw[48 + r], p2 = raw[96 + r];
    float g0 = R[0]*p0 + R[1]*p1 + R[2]*p2 + T[0];
    float g1 = R[3]*p0 + R[4]*p1 + R[5]*p2 + T[1];
    float g2 = R[6]*p0 + R[7]*p1 + R[8]*p2 + T[2];
    float* qp = ws + OFF_QPTS + n * 144 + r * 3;
    qp[0] = g0; qp[1] = g1; qp[2] = g2;
  } else {
    const int r2 = r - 48;
    const float* raw = ws + OFF_KVPRAW + n * 432;
    float p0 = raw[r2], p1 = raw[144 + r2], p2 = raw[288 + r2];
    float g0 = R[0]*p0 + R[1]*p1 + R[2]*p2 + T[0];
    float g1 = R[3]*p0 + R[4]*p1 + R[5]*p2 + T[1];
    float g2 = R[6]*p0 + R[7]*p1 + R[8]*p2 + T[2];
    const int h = r2 / 12, p = r2 % 12;
    if (p < 4) {
      float* kp = ws + OFF_KPTS + n * 144 + (h * 4 + p) * 3;
      kp[0] = g0; kp[1] = g1; kp[2] = g2;
    } else {
      float* vp = ws + OFF_VPTS + n * 288 + (h * 8 + (p - 4)) * 3;
      vp[0] = g0; vp[1] = g1; vp[2] = g2;
    }
  }
}

// ---------------------------------------------------------------- K2b: transpose K, K_pts; build M = [V|VPTS]^T bf16 (unchanged)
__global__ void __launch_bounds__(256)
k2b_tr(float* __restrict__ ws) {
  const int i = blockIdx.x * 256 + threadIdx.x;
  if (i < 147456) {
    const int n = i / 192, cc = i % 192;
    (ws + OFF_KT)[cc * 768 + n] = (ws + OFF_K)[i];
  } else if (i < 258048) {
    const int i2 = i - 147456;
    const int n = i2 / 144, r = i2 % 144;
    (ws + OFF_KPT)[r * 768 + n] = (ws + OFF_KPTS)[i2];
  } else {
    const int im = i - 258048;                 // [0, 393216)
    const int row = im / 768, p = im - row * 768;
    unsigned short* M = (unsigned short*)(ws + OFF_MT);
    float val = 0.0f;
    if (row < 480) {
      const int hh = row / 40, c = row - hh * 40;
      const int pl = p & 63;
      const int k = (p & ~63) | (((pl & 7) << 3) | (pl >> 3));   // inv-pi (involution)
      val = (c < 16) ? (ws + OFF_V)[k * 192 + hh * 16 + c]
                     : (ws + OFF_VPTS)[k * 288 + hh * 24 + (c - 16)];
    }
    M[row * 768 + p] = f2bf(val);
  }
}

// ---------------------------------------------------------------- KS: S[q][h][k] (unchanged)
__global__ void __launch_bounds__(256)
ks_scores(const float* __restrict__ mask, const float* __restrict__ bb,
          const float* __restrict__ hwin, float* __restrict__ ws) {
  const int k0 = blockIdx.x * 64;
  const int q0 = blockIdx.y * 16;
  const int t = threadIdx.x;
  const int g = t >> 6, kl = t & 63;
  const int kg = k0 + kl;

  const float* ktr  = ws + OFF_KT;
  const float* kptr = ws + OFF_KPT;
  float F[3][28];
  #pragma unroll
  for (int j = 0; j < 3; ++j) {
    const int h = g + 4 * j;
    #pragma unroll
    for (int c = 0; c < 16; ++c) F[j][c] = ktr[(h * 16 + c) * 768 + kg];
    #pragma unroll
    for (int r = 0; r < 12; ++r) F[j][16 + r] = kptr[(h * 12 + r) * 768 + kg];
  }
  float hw3[3], bb3[3];
  #pragma unroll
  for (int j = 0; j < 3; ++j) {
    const int h = g + 4 * j;
    hw3[j] = logf(1.0f + expf(hwin[h])) * 0.13608276348795434f;  // softplus*sqrt(1/54)
    bb3[j] = 0.57735026918962576f * bb[h];
  }
  const float maskk = mask[kg];
  unsigned short* Sg = (unsigned short*)(ws + OFF_S);

  for (int qi = 0; qi < 16; ++qi) {
    const int q = q0 + qi;
    const float mterm = INF_ * (mask[q] * maskk - 1.0f);
    const float* qrow  = ws + OFF_Q    + q * 192;   // uniform -> s_loads
    const float* qprow = ws + OFF_QPTS + q * 144;
    #pragma unroll
    for (int j = 0; j < 3; ++j) {
      const int h = g + 4 * j;
      float qk = 0.f;
      #pragma unroll
      for (int c = 0; c < 16; ++c) qk += qrow[h * 16 + c] * F[j][c];
      float pt = 0.f;
      #pragma unroll
      for (int r = 0; r < 12; ++r) {
        const float d = qprow[h * 12 + r] - F[j][16 + r];
        pt += d * d;
      }
      const float S = 0.14433756729740643f * qk - 0.5f * hw3[j] * pt
                    + bb3[j] + mterm;
      Sg[(size_t)(q * 12 + h) * 768 + kg] = f2bf(S);
    }
  }
}

// ---------------------------------------------------------------- K3: fused single-z-pass attention
// R3: z staged via async global_load_lds DMA into a 32KB f32 staging buffer,
// double-pumped at chunk granularity: DMA(i+1) issues right after pack(i)
// releases staging and flies across bias/w/phaseD; drained by the loop-top
// __syncthreads (vmcnt(0) there is exactly the rendezvous). Syncs A/B/C are
// lgkmcnt-only so the DMA + hoisted M loads never drain mid-chunk. M-frags
// (16 dwordx4) hoisted to chunk top so they are OLDER than the DMA -> the
// compiler's counted vmcnt for phase D's MFMAs leaves the DMA in flight.
// LDS 75.5KB -> 2 blocks/CU; launch_bounds(256,2) so nothing spills.
#define ZT_S 72
#define ZR_S 136
#define WT_S 72
__global__ void __launch_bounds__(256, 2)
k3_fused(const float* __restrict__ z, const float* __restrict__ rot,
         const float* __restrict__ trans, const float* __restrict__ Wb,
         float* __restrict__ ws) {
  const int q = blockIdx.x, t = threadIdx.x;
  const int g = t >> 6, kl = t & 63;
  const int l15 = kl & 15, lq = kl >> 4;

  __shared__ float stage[64 * 128];           // 32768 B raw f32 z chunk
  __shared__ unsigned short zT[128 * ZT_S];   // 18432 B
  __shared__ unsigned short zR[64 * ZR_S];    // 17408 B
  __shared__ unsigned short wT[16 * WT_S];    // 2304 B
  __shared__ float bias_s[64 * 13];           // 3328 B
  __shared__ float lsum[12], linv[12];
  __shared__ float opt_raw[288];

  // resident bias A-frags: A[m=h][c] = Wb[c][h] (rows 12..15 zero)
  s16x8 wbA[4];
  #pragma unroll
  for (int kk = 0; kk < 4; ++kk) {
    #pragma unroll
    for (int j = 0; j < 8; ++j) {
      float v = (l15 < 12) ? Wb[(kk * 32 + lq * 8 + j) * 12 + l15] : 0.0f;
      wbA[kk][j] = (short)f2bf(v);
    }
  }

  const unsigned short* Sg = (const unsigned short*)(ws + OFF_S);
  const char* zbytes = (const char*)z + (size_t)q * 768 * 512;  // q-slice: 768 k-rows x 512 B, chunk = contiguous 32KB
  const unsigned short* mbase = (const unsigned short*)(ws + OFF_MT)
                              + (size_t)(g * 128 + l15) * 768 + lq * 8;

  float l3[3] = {0.f, 0.f, 0.f};
  f32x4 opA = {0.f,0.f,0.f,0.f}, opB = {0.f,0.f,0.f,0.f};
  f32x4 acc[8];
  #pragma unroll
  for (int i = 0; i < 8; ++i) acc[i] = (f32x4){0.f,0.f,0.f,0.f};

  const int kb = t >> 5, c4 = t & 31;

  // ---- prologue: DMA chunk 0 into staging (wave g covers bytes [g*8K, (g+1)*8K))
  #pragma unroll
  for (int j = 0; j < 8; ++j) {
    const int boff = (g * 8 + j) * 1024;
    gload_lds16(zbytes + boff + kl * 16, (char*)stage + boff);
  }

  for (int k0 = 0; k0 < NN; k0 += 64) {
    __syncthreads();   // vmcnt(0): staging(i) DMA complete; phase D(i-1) done with zT/wT

    // ---- issue S + M loads for this chunk (older than the upcoming DMA)
    unsigned short Sc[3];
    #pragma unroll
    for (int j = 0; j < 3; ++j)
      Sc[j] = Sg[(size_t)(q * 12 + (g + 4 * j)) * 768 + k0 + kl];
    s16x8 mfr[16];
    {
      const unsigned short* mp = mbase + k0;
      #pragma unroll
      for (int ti = 0; ti < 8; ++ti) {
        mfr[2 * ti]     = *(const s16x8*)(mp);
        mfr[2 * ti + 1] = *(const s16x8*)(mp + 32);
        mp += 16 * 768;
      }
    }

    // ---- pack staging -> zR + zT (zT e-rotated, pi(k)=(k&7)*8+(k>>3))
    #pragma unroll
    for (int half = 0; half < 2; ++half) {
      float4 zv[4];
      #pragma unroll
      for (int j = 0; j < 4; ++j)
        zv[j] = *(const float4*)&stage[(size_t)(kb + 8 * (half * 4 + j)) * 128 + c4 * 4];
      #pragma unroll
      for (int j = 0; j < 4; ++j) {
        uint2 d;
        d.x = pk2(zv[j].x, zv[j].y);
        d.y = pk2(zv[j].z, zv[j].w);
        *(uint2*)&zR[(kb + 8 * (half * 4 + j)) * ZR_S + c4 * 4] = d;
      }
      #pragma unroll
      for (int w = 0; w < 4; ++w) {
        const int e = ((c4 >> 1) + w) & 3;
        uint2 d;
        d.x = pk2(((const float*)&zv[0])[e], ((const float*)&zv[1])[e]);
        d.y = pk2(((const float*)&zv[2])[e], ((const float*)&zv[3])[e]);
        *(uint2*)&zT[(c4 * 4 + e) * ZT_S + kb * 8 + half * 4] = d;
      }
    }
    LDS_BARRIER();   // sync A: staging reads done; zR/zT visible. (M/S stay in flight)

    // ---- DMA next chunk into staging; flies across bias/w/phase D
    if (k0 + 64 < NN) {
      const char* src = zbytes + (size_t)(k0 + 64) * 512;
      #pragma unroll
      for (int j = 0; j < 8; ++j) {
        const int boff = (g * 8 + j) * 1024;
        gload_lds16(src + boff + kl * 16, (char*)stage + boff);
      }
    }

    // ---- bias MFMA: wave g -> k-tile g; D row = h, col = k-in-tile
    {
      f32x4 bd = {0.f,0.f,0.f,0.f};
      #pragma unroll
      for (int kk = 0; kk < 4; ++kk) {
        s16x8 bf = *(const s16x8*)&zR[(g * 16 + l15) * ZR_S + kk * 32 + lq * 8];
        bd = __builtin_amdgcn_mfma_f32_16x16x32_bf16(wbA[kk], bf, bd, 0, 0, 0);
      }
      #pragma unroll
      for (int r = 0; r < 4; ++r) {
        const int h = lq * 4 + r;
        if (h < 12) bias_s[(g * 16 + l15) * 13 + h] = bd[r];
      }
    }
    LDS_BARRIER();   // sync B: bias_s visible (DMA in flight)

    // ---- w = exp(S + c2*bias); store wT (bf16, pi-order); accumulate l
    {
      #pragma unroll
      for (int j = 0; j < 3; ++j) {
        const int h = g + 4 * j;
        const float Sv = bf2f(Sc[j]);
        const float wv = __expf(Sv + 0.57735026918962576f * bias_s[kl * 13 + h]);
        l3[j] += wv;
        wT[h * WT_S + ((kl & 7) * 8 + (kl >> 3))] = f2bf(wv);
      }
    }
    LDS_BARRIER();   // sync C: wT visible (DMA in flight)

    // ---- phase D: all-MFMA. o_pair from zT (LDS), o/o_pt from mfr regs.
    const s16x8 af0 = *(const s16x8*)&wT[l15 * WT_S + lq * 8];
    const s16x8 af1 = *(const s16x8*)&wT[l15 * WT_S + 32 + lq * 8];
    {
      s16x8 b0 = *(const s16x8*)&zT[((2 * g)     * 16 + l15) * ZT_S + lq * 8];
      s16x8 b1 = *(const s16x8*)&zT[((2 * g)     * 16 + l15) * ZT_S + 32 + lq * 8];
      s16x8 b2 = *(const s16x8*)&zT[((2 * g + 1) * 16 + l15) * ZT_S + lq * 8];
      s16x8 b3 = *(const s16x8*)&zT[((2 * g + 1) * 16 + l15) * ZT_S + 32 + lq * 8];
      opA = __builtin_amdgcn_mfma_f32_16x16x32_bf16(af0, b0, opA, 0, 0, 0);
      opA = __builtin_amdgcn_mfma_f32_16x16x32_bf16(af1, b1, opA, 0, 0, 0);
      opB = __builtin_amdgcn_mfma_f32_16x16x32_bf16(af0, b2, opB, 0, 0, 0);
      opB = __builtin_amdgcn_mfma_f32_16x16x32_bf16(af1, b3, opB, 0, 0, 0);
    }
    #pragma unroll
    for (int ti = 0; ti < 8; ++ti) {
      acc[ti] = __builtin_amdgcn_mfma_f32_16x16x32_bf16(af0, mfr[2 * ti],     acc[ti], 0, 0, 0);
      acc[ti] = __builtin_amdgcn_mfma_f32_16x16x32_bf16(af1, mfr[2 * ti + 1], acc[ti], 0, 0, 0);
    }
  }

  // ---- l reduction
  #pragma unroll
  for (int j = 0; j < 3; ++j) {
    float v = l3[j];
    for (int off = 1; off < 64; off <<= 1) v += __shfl_xor(v, off, 64);
    l3[j] = v;
  }
  if (kl == 0) { lsum[g] = l3[0]; lsum[g + 4] = l3[1]; lsum[g + 8] = l3[2]; }
  __syncthreads();
  if (t < 12) linv[t] = 1.0f / lsum[t];
  __syncthreads();

  float* cat = ws + OFF_CAT + (size_t)q * 2112;

  // o_pair
  #pragma unroll
  for (int r = 0; r < 4; ++r) {
    const int h = lq * 4 + r;
    if (h < 12) {
      cat[576 + h * 128 + (2 * g)     * 16 + l15] = opA[r] * linv[h];
      cat[576 + h * 128 + (2 * g + 1) * 16 + l15] = opB[r] * linv[h];
    }
  }

  // o / o_pt extraction: wave g owns col-tiles g*8..g*8+7; col cg -> (hh, c)
  #pragma unroll
  for (int ti = 0; ti < 8; ++ti) {
    const int cg = (g * 8 + ti) * 16 + l15;
    const int hh = cg / 40;
    const int c  = cg - hh * 40;
    #pragma unroll
    for (int r = 0; r < 4; ++r) {
      if (hh < 12 && (lq * 4 + r) == hh) {
        const float val = acc[ti][r] * linv[hh];
        if (c < 16) cat[hh * 16 + c] = val;
        else        opt_raw[hh * 24 + (c - 16)] = val;
      }
    }
  }
  __syncthreads();

  if (t < 96) {
    const int h = t >> 3, p = t & 7;
    const float* R = rot + q * 9;
    const float* T = trans + q * 3;
    const float g0 = opt_raw[h * 24 + p * 3 + 0] - T[0];
    const float g1 = opt_raw[h * 24 + p * 3 + 1] - T[1];
    const float g2 = opt_raw[h * 24 + p * 3 + 2] - T[2];
    const float x  = R[0]*g0 + R[3]*g1 + R[6]*g2;
    const float y  = R[1]*g0 + R[4]*g1 + R[7]*g2;
    const float zc = R[2]*g0 + R[5]*g1 + R[8]*g2;
    const int hp = h * 8 + p;
    cat[192 + hp] = x;
    cat[288 + hp] = y;
    cat[384 + hp] = zc;
    cat[480 + hp] = sqrtf(x*x + y*y + zc*zc + 1e-8f);
  }
}

// ---------------------------------------------------------------- K5: out GEMM 64m x 64n, K-split 6, atomic
__global__ void __launch_bounds__(256)
k5_init(const float* __restrict__ bout, float* __restrict__ out) {
  const int i = blockIdx.x * 256 + threadIdx.x;  // 294912
  out[i] = bout[i % 384];
}

__global__ void __launch_bounds__(256)
k5_out(const float* __restrict__ Wout, const float* __restrict__ ws,
       float* __restrict__ out) {
  const int n0  = blockIdx.x * 64;    // 6
  const int m0  = blockIdx.y * 64;    // 12
  const int ks0 = blockIdx.z * 352;   // 6
  const int t = threadIdx.x;

  __shared__ float As[32 * 68];   // [k][m]
  __shared__ float Bs[32 * 68];   // [k][n]
  const int tx = t & 15, ty = t >> 4;
  float acc[4][4] = {{0.f}};

  const float* catg = ws + OFF_CAT;
  for (int kc = 0; kc < 352; kc += 32) {
    __syncthreads();
    #pragma unroll
    for (int p = 0; p < 2; ++p) {            // A: 64 m x 32 k (float4 read, scatter write)
      const int idx = t + 256 * p;
      const int m = idx >> 3, c4 = idx & 7;
      const float4 v = *(const float4*)&catg[(size_t)(m0 + m) * 2112 + ks0 + kc + c4 * 4];
      As[(c4 * 4 + 0) * 68 + m] = v.x;
      As[(c4 * 4 + 1) * 68 + m] = v.y;
      As[(c4 * 4 + 2) * 68 + m] = v.z;
      As[(c4 * 4 + 3) * 68 + m] = v.w;
    }
    #pragma unroll
    for (int p = 0; p < 8; ++p) {            // B: 32 k x 64 n (coalesced)
      const int idx = t + 256 * p;
      const int k = idx >> 6, n = idx & 63;
      Bs[k * 68 + n] = Wout[(size_t)(ks0 + kc + k) * 384 + n0 + n];
    }
    __syncthreads();
    #pragma unroll 8
    for (int k = 0; k < 32; ++k) {
      const float4 a4 = *(const float4*)&As[k * 68 + ty * 4];
      const float4 b4 = *(const float4*)&Bs[k * 68 + tx * 4];
      acc[0][0] += a4.x * b4.x; acc[0][1] += a4.x * b4.y; acc[0][2] += a4.x * b4.z; acc[0][3] += a4.x * b4.w;
      acc[1][0] += a4.y * b4.x; acc[1][1] += a4.y * b4.y; acc[1][2] += a4.y * b4.z; acc[1][3] += a4.y * b4.w;
      acc[2][0] += a4.z * b4.x; acc[2][1] += a4.z * b4.y; acc[2][2] += a4.z * b4.z; acc[2][3] += a4.z * b4.w;
      acc[3][0] += a4.w * b4.x; acc[3][1] += a4.w * b4.y; acc[3][2] += a4.w * b4.z; acc[3][3] += a4.w * b4.w;
    }
  }
  #pragma unroll
  for (int r = 0; r < 4; ++r)
    #pragma unroll
    for (int c = 0; c < 4; ++c)
      atomicAdd(&out[(size_t)(m0 + ty * 4 + r) * 384 + n0 + tx * 4 + c], acc[r][c]);
}

// ----------------------------------------------------------------
extern "C" void kernel_launch(void* const* d_in, const int* in_sizes, int n_in,
                              void* d_out, int out_size, void* d_ws, size_t ws_size,
                              hipStream_t stream) {
  const float* s     = (const float*)d_in[0];
  const float* z     = (const float*)d_in[1];
  const float* rot   = (const float*)d_in[2];
  const float* trans = (const float*)d_in[3];
  const float* mask  = (const float*)d_in[4];
  const float* Wq    = (const float*)d_in[5];
  const float* bq    = (const float*)d_in[6];
  const float* Wqp   = (const float*)d_in[7];
  const float* bqp   = (const float*)d_in[8];
  const float* Wkv   = (const float*)d_in[9];
  const float* bkv   = (const float*)d_in[10];
  const float* Wkvp  = (const float*)d_in[11];
  const float* bkvp  = (const float*)d_in[12];
  const float* Wb    = (const float*)d_in[13];
  const float* bb    = (const float*)d_in[14];
  const float* hw    = (const float*)d_in[15];
  const float* Wout  = (const float*)d_in[16];
  const float* bout  = (const float*)d_in[17];
  float* out = (float*)d_out;
  float* ws  = (float*)d_ws;

  k1_proj<<<dim3(72, 6), 256, 0, stream>>>(s, Wq, bq, Wqp, bqp, Wkv, bkv, Wkvp, bkvp, ws);
  k2_rot <<<576, 256, 0, stream>>>(rot, trans, ws);
  k2b_tr <<<2544, 256, 0, stream>>>(ws);
  ks_scores<<<dim3(12, 48), 256, 0, stream>>>(mask, bb, hw, ws);
  k3_fused<<<NN, 256, 0, stream>>>(z, rot, trans, Wb, ws);
  k5_init<<<1152, 256, 0, stream>>>(bout, out);
  k5_out<<<dim3(6, 12, 6), 256, 0, stream>>>(Wout, ws, out);
}